// Round 1
// baseline (199.226 us; speedup 1.0000x reference)
//
#include <hip/hip_runtime.h>
#include <hip/hip_bf16.h>
#include <stdint.h>

#define T_DIM 2048
#define N_DIM 512
#define DV_DIM 128
#define NH 16          // B*H
#define BM 64
#define NBLK 32        // T/BM

typedef __bf16 bf16x8 __attribute__((ext_vector_type(8)));
typedef float f32x4 __attribute__((ext_vector_type(4)));
typedef float f32x2 __attribute__((ext_vector_type(2)));
typedef unsigned int u32x4 __attribute__((ext_vector_type(4)));

__device__ __forceinline__ unsigned bf16rne(float x) {
  unsigned u = __builtin_bit_cast(unsigned, x);
  return (u + 0x7FFFu + ((u >> 16) & 1u)) >> 16;
}

__device__ __forceinline__ void load_lds16(const void* g, void* l) {
  __builtin_amdgcn_global_load_lds((const __attribute__((address_space(1))) void*)g,
                                   (__attribute__((address_space(3))) void*)l, 16, 0, 0);
}

// ---------------- RoPE: Q fp32 -> QR bf16 ----------------
__global__ void rope_kernel(const float* __restrict__ Q, const float* __restrict__ freqs,
                            unsigned int* __restrict__ qrOut) {
  const int total = NH * T_DIM * (N_DIM / 2);  // pairs
  for (int p = blockIdx.x * blockDim.x + threadIdx.x; p < total;
       p += gridDim.x * blockDim.x) {
    int n2 = p & 255;            // N/2 = 256
    int t = (p >> 8) & 2047;
    float f = freqs[2 * n2];
    f32x2 q = *(const f32x2*)(Q + 2 * (size_t)p);
    float ph = (float)t * f;
    ph = ph - floorf(ph);                 // revolutions in [0,1)
    float sn = __builtin_amdgcn_sinf(ph); // sin(2*pi*ph)
    float cn = __builtin_amdgcn_cosf(ph);
    float o0 = q.x * cn - q.y * sn;
    float o1 = q.y * cn + q.x * sn;
    qrOut[p] = bf16rne(o0) | (bf16rne(o1) << 16);
  }
}

// ---------------- V transpose: V fp32 [bh][t][d] -> VT bf16 [bh][d][t] ----------------
__global__ void vtrans_kernel(const float* __restrict__ V, unsigned short* __restrict__ vtOut) {
  __shared__ unsigned short tile[64][65];
  int blk = blockIdx.x;
  int bh = blk >> 6;
  int tt = (blk >> 1) & 31;
  int td = blk & 1;
  int t0 = tt * 64, d0 = td * 64;
  const float* src = V + ((size_t)bh * T_DIM + t0) * DV_DIM + d0;
#pragma unroll
  for (int it = 0; it < 16; ++it) {
    int sl = it * 256 + threadIdx.x;
    int r = sl >> 6, c = sl & 63;
    tile[r][c] = (unsigned short)bf16rne(src[r * DV_DIM + c]);
  }
  __syncthreads();
  unsigned short* dst = vtOut + ((size_t)bh * DV_DIM + d0) * T_DIM + t0;
#pragma unroll
  for (int it = 0; it < 16; ++it) {
    int sl = it * 256 + threadIdx.x;
    int r = sl >> 6, c = sl & 63;  // r = d-local, c = t-local
    dst[r * T_DIM + c] = tile[c][r];
  }
}

// ---------------- fused masked attention ----------------
__global__ __launch_bounds__(256, 1)
void attn_kernel(const unsigned short* __restrict__ qr,
                 const unsigned short* __restrict__ vt,
                 float* __restrict__ out) {
  __shared__ unsigned short k_lds[64 * 512];    // 64 KB, row stride 1024 B, XOR-swizzled
  __shared__ unsigned short vt_lds[128 * 64];   // 16 KB, row stride 128 B, XOR-swizzled
  __shared__ unsigned short s_lds[8 * 16 * 72]; // per (tile,wave): [16][72] bf16

  const int wg = blockIdx.x;
  const int bh = (wg & 7) * 2 + ((wg >> 3) & 1);  // heads grouped per XCD
  const int p = wg >> 4;                          // 0..15
  const int iA = p, iB = 31 - p;

  const int tid = threadIdx.x;
  const int w = tid >> 6;
  const int lane = tid & 63;
  const int lh = lane & 15;
  const int lg = lane >> 4;

  const unsigned short* qr_h = qr + (size_t)bh * (T_DIM * N_DIM);
  const unsigned short* vt_h = vt + (size_t)bh * (DV_DIM * T_DIM);

  // Q fragments in registers: [tile][ks], A-frag = row (l&15), k = 8*(l>>4)+i
  u32x4 qfA[16], qfB[16];
  {
    const unsigned short* pa = qr_h + (size_t)(iA * BM + w * 16 + lh) * N_DIM + lg * 8;
    const unsigned short* pb = qr_h + (size_t)(iB * BM + w * 16 + lh) * N_DIM + lg * 8;
#pragma unroll
    for (int ks = 0; ks < 16; ++ks) {
      qfA[ks] = *(const u32x4*)(pa + ks * 32);
      qfB[ks] = *(const u32x4*)(pb + ks * 32);
    }
  }

  const f32x4 fzero = {0.f, 0.f, 0.f, 0.f};
  f32x4 oA[8], oB[8];
#pragma unroll
  for (int i = 0; i < 8; ++i) { oA[i] = fzero; oB[i] = fzero; }

  const int sregA = w * (16 * 72);
  const int sregB = (4 + w) * (16 * 72);

  for (int j = 0; j <= iB; ++j) {
    // ---- stage K block j (rows j*64..j*64+63 of QR) and VT block j ----
    {
      const char* kbase = (const char*)(qr_h + (size_t)(j * 64) * N_DIM);
#pragma unroll
      for (int it = 0; it < 16; ++it) {
        int slot = it * 256 + tid;          // 0..4095, 16B each
        int s = slot >> 6;
        int c = (slot & 63) << 4;
        int csrc = c ^ ((s & 7) << 4);      // pre-swizzled source
        load_lds16(kbase + s * 1024 + csrc, (char*)k_lds + slot * 16);
      }
      const char* vbase = (const char*)(vt_h + j * 64);
#pragma unroll
      for (int it = 0; it < 4; ++it) {
        int slot = it * 256 + tid;          // 0..1023
        int d = slot >> 3;
        int c = (slot & 7) << 4;
        int csrc = c ^ ((d & 7) << 4);
        load_lds16(vbase + (size_t)d * (T_DIM * 2) + csrc, (char*)vt_lds + slot * 16);
      }
    }
    __syncthreads();

    const bool actA = (j <= iA);
    f32x4 sA[4], sB[4];
#pragma unroll
    for (int i = 0; i < 4; ++i) { sA[i] = fzero; sB[i] = fzero; }

    // ---- QK^T: S[t][s], K-frags shared between both Q-tiles ----
#pragma unroll
    for (int ks = 0; ks < 16; ++ks) {
      bf16x8 kf[4];
#pragma unroll
      for (int sf = 0; sf < 4; ++sf) {
        int srow = sf * 16 + lh;
        int cb = ((ks * 32 + lg * 8) * 2) ^ ((srow & 7) << 4);
        kf[sf] = *(const bf16x8*)((const char*)k_lds + srow * 1024 + cb);
      }
      bf16x8 qa = __builtin_bit_cast(bf16x8, qfA[ks]);
      bf16x8 qb = __builtin_bit_cast(bf16x8, qfB[ks]);
#pragma unroll
      for (int sf = 0; sf < 4; ++sf) {
        if (actA) sA[sf] = __builtin_amdgcn_mfma_f32_16x16x32_bf16(qa, kf[sf], sA[sf], 0, 0, 0);
        sB[sf] = __builtin_amdgcn_mfma_f32_16x16x32_bf16(qb, kf[sf], sB[sf], 0, 0, 0);
      }
    }

    // ---- mask (strict causal) + bf16 convert + store S ----
    const int srow_base = j * 64;
    if (actA) {
      const int t0 = iA * 64 + w * 16 + lg * 4;
      const bool diag = (j == iA);
#pragma unroll
      for (int sf = 0; sf < 4; ++sf)
#pragma unroll
        for (int r = 0; r < 4; ++r) {
          float v = sA[sf][r];
          if (diag && (srow_base + sf * 16 + lh) >= (t0 + r)) v = 0.f;
          s_lds[sregA + (lg * 4 + r) * 72 + sf * 16 + lh] = (unsigned short)bf16rne(v);
        }
    }
    {
      const int t0 = iB * 64 + w * 16 + lg * 4;
      const bool diag = (j == iB);
#pragma unroll
      for (int sf = 0; sf < 4; ++sf)
#pragma unroll
        for (int r = 0; r < 4; ++r) {
          float v = sB[sf][r];
          if (diag && (srow_base + sf * 16 + lh) >= (t0 + r)) v = 0.f;
          s_lds[sregB + (lg * 4 + r) * 72 + sf * 16 + lh] = (unsigned short)bf16rne(v);
        }
    }

    // ---- PV: O += S * V  (VT rows as B^T), VT-frags shared between tiles ----
#pragma unroll
    for (int ks2 = 0; ks2 < 2; ++ks2) {
      bf16x8 pa = *(const bf16x8*)&s_lds[sregA + lh * 72 + ks2 * 32 + lg * 8];
      bf16x8 pb = *(const bf16x8*)&s_lds[sregB + lh * 72 + ks2 * 32 + lg * 8];
#pragma unroll
      for (int df = 0; df < 8; ++df) {
        int d = df * 16 + lh;
        int cb = ((ks2 * 32 + lg * 8) * 2) ^ ((d & 7) << 4);
        bf16x8 vf = *(const bf16x8*)((const char*)vt_lds + d * 128 + cb);
        if (actA) oA[df] = __builtin_amdgcn_mfma_f32_16x16x32_bf16(pa, vf, oA[df], 0, 0, 0);
        oB[df] = __builtin_amdgcn_mfma_f32_16x16x32_bf16(pb, vf, oB[df], 0, 0, 0);
      }
    }
    __syncthreads();
  }

  // ---- epilogue: fp32 out, D-frag mapping col=l&15, row=4*(l>>4)+r ----
  {
    float* ob = out + ((size_t)bh * T_DIM + iA * 64 + w * 16 + lg * 4) * DV_DIM;
#pragma unroll
    for (int df = 0; df < 8; ++df)
#pragma unroll
      for (int r = 0; r < 4; ++r)
        ob[(size_t)r * DV_DIM + df * 16 + lh] = oA[df][r];
  }
  {
    float* ob = out + ((size_t)bh * T_DIM + iB * 64 + w * 16 + lg * 4) * DV_DIM;
#pragma unroll
    for (int df = 0; df < 8; ++df)
#pragma unroll
      for (int r = 0; r < 4; ++r)
        ob[(size_t)r * DV_DIM + df * 16 + lh] = oB[df][r];
  }
}

extern "C" void kernel_launch(void* const* d_in, const int* in_sizes, int n_in,
                              void* d_out, int out_size, void* d_ws, size_t ws_size,
                              hipStream_t stream) {
  const float* Q = (const float*)d_in[0];
  const float* V = (const float*)d_in[1];
  const float* freqs = (const float*)d_in[2];
  float* out = (float*)d_out;

  unsigned short* qr = (unsigned short*)d_ws;                       // 16*2048*512 bf16
  unsigned short* vt = qr + (size_t)NH * T_DIM * N_DIM;             // 16*128*2048 bf16

  hipLaunchKernelGGL(rope_kernel, dim3(2048), dim3(256), 0, stream,
                     Q, freqs, (unsigned int*)qr);
  hipLaunchKernelGGL(vtrans_kernel, dim3(NH * 32 * 2), dim3(256), 0, stream, V, vt);
  hipLaunchKernelGGL(attn_kernel, dim3(256), dim3(256), 0, stream, qr, vt, out);
}

// Round 2
// 154.738 us; speedup vs baseline: 1.2875x; 1.2875x over previous
//
#include <hip/hip_runtime.h>
#include <hip/hip_bf16.h>
#include <stdint.h>

#define T_DIM 2048
#define N_DIM 512
#define DV_DIM 128
#define NH 16          // B*H

typedef __bf16 bf16x8 __attribute__((ext_vector_type(8)));
typedef float f32x4 __attribute__((ext_vector_type(4)));
typedef float f32x2 __attribute__((ext_vector_type(2)));
typedef unsigned int u32x4 __attribute__((ext_vector_type(4)));

__device__ __forceinline__ unsigned bf16rne(float x) {
  unsigned u = __builtin_bit_cast(unsigned, x);
  return (u + 0x7FFFu + ((u >> 16) & 1u)) >> 16;
}

__device__ __forceinline__ void load_lds16(const void* g, void* l) {
  __builtin_amdgcn_global_load_lds((const __attribute__((address_space(1))) void*)g,
                                   (__attribute__((address_space(3))) void*)l, 16, 0, 0);
}

// ---------------- RoPE: Q fp32 -> QR bf16  [bh][t][n] ----------------
__global__ void rope_kernel(const float* __restrict__ Q, const float* __restrict__ freqs,
                            unsigned int* __restrict__ qrOut) {
  const int total = NH * T_DIM * (N_DIM / 2);  // pairs
  for (int p = blockIdx.x * blockDim.x + threadIdx.x; p < total;
       p += gridDim.x * blockDim.x) {
    int n2 = p & 255;            // N/2 = 256
    int t = (p >> 8) & 2047;
    float f = freqs[2 * n2];
    f32x2 q = *(const f32x2*)(Q + 2 * (size_t)p);
    float ph = (float)t * f;
    ph = ph - floorf(ph);                 // revolutions in [0,1)
    float sn = __builtin_amdgcn_sinf(ph);
    float cn = __builtin_amdgcn_cosf(ph);
    float o0 = q.x * cn - q.y * sn;
    float o1 = q.y * cn + q.x * sn;
    qrOut[p] = bf16rne(o0) | (bf16rne(o1) << 16);
  }
}

// ---------------- V -> blocked VT bf16: vtb[bh][t/16][d][t%16] ----------------
__global__ void vtrans_kernel(const float* __restrict__ V, unsigned short* __restrict__ vtb) {
  __shared__ unsigned short tile[64][65];
  int blk = blockIdx.x;
  int bh = blk >> 6;
  int tt = (blk >> 1) & 31;  // t-tile (64 rows)
  int td = blk & 1;          // d-half (64)
  int t0 = tt * 64, d0 = td * 64;
  const float* src = V + ((size_t)bh * T_DIM + t0) * DV_DIM + d0;
  int tid = threadIdx.x;
#pragma unroll
  for (int it = 0; it < 16; ++it) {
    int sl = it * 256 + tid;
    int r = sl >> 6, c = sl & 63;   // r = t-local, c = d-local
    tile[r][c] = (unsigned short)bf16rne(src[r * DV_DIM + c]);
  }
  __syncthreads();
  // each thread: one (j16-local, d-local) -> 16 contiguous shorts (32B)
  int jl = tid >> 6;       // 0..3
  int dl = tid & 63;       // 0..63
  unsigned short tmp[16];
#pragma unroll
  for (int k = 0; k < 16; ++k) tmp[k] = tile[jl * 16 + k][dl];
  unsigned short* dst = vtb + (size_t)bh * (128 * DV_DIM * 16)
                        + (size_t)(tt * 4 + jl) * (DV_DIM * 16)
                        + (size_t)(d0 + dl) * 16;
  *(u32x4*)(dst) = *(u32x4*)(tmp);
  *(u32x4*)(dst + 8) = *(u32x4*)(tmp + 8);
}

// ---------------- fused masked attention ----------------
// 1024 wgs x 128 thr. wg = (REG 0..31, head, jpar). 2 waves; wave w owns rows
// t0U = REG*64 + w*16 and t0L = REG*64+32 + w*16 (M=32, k-frags shared).
// K staged in 16-row blocks, double-buffered; V direct global->reg; S via
// per-wave LDS; output combined across jpar by f32 atomicAdd.
__global__ __launch_bounds__(128, 2)
void attn_kernel(const unsigned short* __restrict__ qr,
                 const unsigned short* __restrict__ vtb,
                 float* __restrict__ out) {
  // k_lds: [buf][ks 0..15][row 0..15][32 bf16] ; 16KB per buf. 64B row stride
  // -> bank-group (4*lh+lg)%8 rotation, conflict-free, imm-offset reads.
  __shared__ unsigned short k_lds[2][16 * 16 * 32];
  // s_lds: [wave][tile][16 rows][32 s] bf16 (1KB each)
  __shared__ unsigned short s_lds[2][2][16 * 32];

  const int tid = threadIdx.x;
  const int w = tid >> 6;
  const int lane = tid & 63;
  const int lh = lane & 15;
  const int lg = lane >> 4;

  // --- block -> (REG, head, jpar); permutation keeps round-robin CU sums flat,
  // heavy regions first ---
  const int bid = blockIdx.x;
  const int m = bid >> 5;          // 0..31
  const int q = m >> 3, i2 = m & 7;
  const int REG = (q == 0) ? (31 - i2) : ((q == 1) ? i2 : ((q == 2) ? (23 - i2) : (8 + i2)));
  const int head = (bid >> 1) & 15;
  const int jpar = bid & 1;
  const int nsteps = 2 * REG + 2;

  const unsigned short* qr_h = qr + (size_t)head * (T_DIM * N_DIM);
  const unsigned short* vtb_h = vtb + (size_t)head * (128 * DV_DIM * 16);

  const int t0U = REG * 64 + w * 16;
  const int t0L = REG * 64 + 32 + w * 16;

  // --- Q fragments in registers: qX[ks] covers k = ks*32 + lg*8 + i ---
  u32x4 qU[16], qL[16];
  {
    const unsigned short* pu = qr_h + (size_t)(t0U + lh) * N_DIM + lg * 8;
    const unsigned short* pl = qr_h + (size_t)(t0L + lh) * N_DIM + lg * 8;
#pragma unroll
    for (int ks = 0; ks < 16; ++ks) {
      qU[ks] = *(const u32x4*)(pu + ks * 32);
      qL[ks] = *(const u32x4*)(pl + ks * 32);
    }
  }

  const f32x4 fzero = {0.f, 0.f, 0.f, 0.f};
  f32x4 oU[8], oL[8];
#pragma unroll
  for (int d = 0; d < 8; ++d) { oU[d] = fzero; oL[d] = fzero; }

  // --- per-thread staging source offsets (bytes), 8 slots of 16B ---
  int goffb[8];
#pragma unroll
  for (int it = 0; it < 8; ++it) {
    int s = it * 128 + tid;
    goffb[it] = ((s >> 2) & 15) * 1024 + (s >> 6) * 64 + (s & 3) * 16;
  }

  u32x4 vfr[8];

  // prologue: stage first block
  {
    const char* base = (const char*)qr_h + (size_t)jpar * 16 * 1024;
#pragma unroll
    for (int it = 0; it < 8; ++it)
      load_lds16(base + goffb[it], (char*)k_lds + (it * 128 + tid) * 16);
  }
  __syncthreads();

  int jl = jpar;
  for (int step = 0; step < nsteps; ++step) {
    const int buf = step & 1;
    // issue next stage (overlaps compute; drained at the barrier below)
    if (step + 1 < nsteps) {
      const char* base = (const char*)qr_h + (size_t)(jl + 2) * 16 * 1024;
      char* dst = (char*)k_lds + (buf ^ 1) * 16384;
#pragma unroll
      for (int it = 0; it < 8; ++it)
        load_lds16(base + goffb[it], dst + (it * 128 + tid) * 16);
    }
    // V fragments for the pair (jl, jl+2): lane's k=8*lg+i -> block lg>>1
    if (!(step & 1)) {
      const unsigned short* vb = vtb_h + (size_t)(jl + 2 * (lg >> 1)) * (DV_DIM * 16) + (lg & 1) * 8;
#pragma unroll
      for (int df = 0; df < 8; ++df)
        vfr[df] = *(const u32x4*)(vb + (df * 16 + lh) * 16);
    }

    // ---- QK^T for this 16-col s-block ----
    f32x4 sU = fzero, sL = fzero;
    const int kbase = buf * 16384 + lh * 64 + lg * 16;  // bytes
#pragma unroll
    for (int ks = 0; ks < 16; ++ks) {
      bf16x8 kf = *(const bf16x8*)((const char*)k_lds + kbase + ks * 1024);
      sU = __builtin_amdgcn_mfma_f32_16x16x32_bf16(__builtin_bit_cast(bf16x8, qU[ks]), kf, sU, 0, 0, 0);
      sL = __builtin_amdgcn_mfma_f32_16x16x32_bf16(__builtin_bit_cast(bf16x8, qL[ks]), kf, sL, 0, 0, 0);
    }

    // ---- mask (strict lower: keep s < t) + bf16 + store to s_lds ----
    {
      const int jl16 = jl * 16;
      const int colb = (step & 1) * 16 + lh;
      unsigned short* su = &s_lds[w][0][0];
      unsigned short* sl_ = &s_lds[w][1][0];
      const bool mU = (jl16 + 16 > t0U);
      const bool mL = (jl16 + 16 > t0L);
#pragma unroll
      for (int r = 0; r < 4; ++r) {
        float vU = sU[r];
        float vL = sL[r];
        if (mU && (jl16 + lh >= t0U + 4 * lg + r)) vU = 0.f;
        if (mL && (jl16 + lh >= t0L + 4 * lg + r)) vL = 0.f;
        su[(4 * lg + r) * 32 + colb] = (unsigned short)bf16rne(vU);
        sl_[(4 * lg + r) * 32 + colb] = (unsigned short)bf16rne(vL);
      }
    }

    // ---- PV every second step (K=32 over the pair's 32 s-columns) ----
    if (step & 1) {
      bf16x8 paU = *(const bf16x8*)((const char*)&s_lds[w][0][0] + lh * 64 + lg * 16);
      bf16x8 paL = *(const bf16x8*)((const char*)&s_lds[w][1][0] + lh * 64 + lg * 16);
#pragma unroll
      for (int df = 0; df < 8; ++df) {
        bf16x8 vb = __builtin_bit_cast(bf16x8, vfr[df]);
        oU[df] = __builtin_amdgcn_mfma_f32_16x16x32_bf16(paU, vb, oU[df], 0, 0, 0);
        oL[df] = __builtin_amdgcn_mfma_f32_16x16x32_bf16(paL, vb, oL[df], 0, 0, 0);
      }
    }

    __syncthreads();  // drains vmcnt: next stage complete; buf free for reuse
    jl += 2;
  }

  // ---- epilogue: atomic-accumulate partial O (jpar halves combine) ----
  {
    float* ob = out + (size_t)head * T_DIM * DV_DIM;
#pragma unroll
    for (int df = 0; df < 8; ++df)
#pragma unroll
      for (int r = 0; r < 4; ++r) {
        atomicAdd(ob + (size_t)(t0U + 4 * lg + r) * DV_DIM + df * 16 + lh, oU[df][r]);
        atomicAdd(ob + (size_t)(t0L + 4 * lg + r) * DV_DIM + df * 16 + lh, oL[df][r]);
      }
  }
}

extern "C" void kernel_launch(void* const* d_in, const int* in_sizes, int n_in,
                              void* d_out, int out_size, void* d_ws, size_t ws_size,
                              hipStream_t stream) {
  const float* Q = (const float*)d_in[0];
  const float* V = (const float*)d_in[1];
  const float* freqs = (const float*)d_in[2];
  float* out = (float*)d_out;

  unsigned short* qr = (unsigned short*)d_ws;                        // 32 MB
  unsigned short* vtb = qr + (size_t)NH * T_DIM * N_DIM;             // 8 MB

  hipMemsetAsync(out, 0, (size_t)NH * T_DIM * DV_DIM * sizeof(float), stream);
  hipLaunchKernelGGL(rope_kernel, dim3(2048), dim3(256), 0, stream,
                     Q, freqs, (unsigned int*)qr);
  hipLaunchKernelGGL(vtrans_kernel, dim3(NH * 32 * 2), dim3(256), 0, stream, V, vtb);
  hipLaunchKernelGGL(attn_kernel, dim3(1024), dim3(128), 0, stream, qr, vtb, out);
}